// Round 6
// baseline (1203.789 us; speedup 1.0000x reference)
//
#include <hip/hip_runtime.h>
#include <hip/hip_bf16.h>

#define BB  4
#define HH  128
#define WW  128
#define CC  192
#define NHH 6
#define KDD 32
#define NTOT (BB*HH*WW*CC)   // 12582912
#define SCALING 0.17677669529663687f

typedef __hip_bfloat16 bf16;

__device__ __forceinline__ float b2f(bf16 v) { return __bfloat162float(v); }
__device__ __forceinline__ bf16  f2b(float v) { return __float2bfloat16(v); }

// unpack 2 packed bf16 (one u32) -> 2 floats (low element first)
__device__ __forceinline__ float2 unpk(unsigned u) {
  union { unsigned v; float f; } lo, hi;
  lo.v = u << 16; hi.v = u & 0xffff0000u;
  return make_float2(lo.f, hi.f);
}

// load 8 consecutive bf16 (16B-aligned) -> 8 floats
__device__ __forceinline__ void load8bf(const bf16* p, float* d) {
  uint4 r = *reinterpret_cast<const uint4*>(p);
  float2 a = unpk(r.x), b = unpk(r.y), c = unpk(r.z), e = unpk(r.w);
  d[0] = a.x; d[1] = a.y; d[2] = b.x; d[3] = b.y;
  d[4] = c.x; d[5] = c.y; d[6] = e.x; d[7] = e.y;
}

// load 32 consecutive floats (16B-aligned) -> dst[32]
__device__ __forceinline__ void load32f(const float* p, float* d) {
  const float4* q = reinterpret_cast<const float4*>(p);
  #pragma unroll
  for (int i = 0; i < 8; ++i) {
    float4 t = q[i];
    d[i*4+0] = t.x; d[i*4+1] = t.y; d[i*4+2] = t.z; d[i*4+3] = t.w;
  }
}

// ---------------- K1: fused QKV projection (fp32 in; q,k bf16; v fp32) ------
__global__ __launch_bounds__(192) void qkv_kernel(
    const float* __restrict__ x,
    const float* __restrict__ Wq, const float* __restrict__ bq,
    const float* __restrict__ Wk, const float* __restrict__ bk,
    const float* __restrict__ Wv, const float* __restrict__ bv,
    bf16* __restrict__ q, bf16* __restrict__ k, float* __restrict__ v) {
  __shared__ float xs[8 * CC];
  const int c = threadIdx.x;
  const int row0 = blockIdx.x * 8;
  {
    const float4* xp = reinterpret_cast<const float4*>(x + row0 * CC) + c * 2;
    float4 a0 = xp[0], a1 = xp[1];
    xs[c*8+0] = a0.x; xs[c*8+1] = a0.y; xs[c*8+2] = a0.z; xs[c*8+3] = a0.w;
    xs[c*8+4] = a1.x; xs[c*8+5] = a1.y; xs[c*8+6] = a1.z; xs[c*8+7] = a1.w;
  }
  __syncthreads();
  float aq[8], ak[8], av[8];
  const float bqf = bq[c], bkf = bk[c], bvf = bv[c];
  #pragma unroll
  for (int r = 0; r < 8; ++r) { aq[r] = bqf; ak[r] = bkf; av[r] = bvf; }
  for (int kk = 0; kk < CC; ++kk) {
    const float wq = Wq[kk * CC + c];
    const float wk = Wk[kk * CC + c];
    const float wv = Wv[kk * CC + c];
    #pragma unroll
    for (int r = 0; r < 8; ++r) {
      const float xv = xs[r * CC + kk];
      aq[r] = fmaf(xv, wq, aq[r]);
      ak[r] = fmaf(xv, wk, ak[r]);
      av[r] = fmaf(xv, wv, av[r]);
    }
  }
  #pragma unroll
  for (int r = 0; r < 8; ++r) {
    const int o = (row0 + r) * CC + c;
    q[o] = f2b(aq[r]);
    k[o] = f2b(ak[r] * SCALING);   // scale AFTER bias, per reference
    v[o] = av[r];
  }
}

// ---------------- K2: depthwise 5x5 conv (LEPE) -> d_out (fp32) -------------
__global__ __launch_bounds__(256) void lepe_kernel(
    const float* __restrict__ v, const float* __restrict__ kw,
    const float* __restrict__ kb, float* __restrict__ lepe) {
  const int idx = blockIdx.x * 256 + threadIdx.x;
  if (idx >= NTOT) return;
  const int c = idx % CC;
  const int w = (idx / CC) % WW;
  const int h = (idx / (CC * WW)) % HH;
  const int b = idx / (CC * WW * HH);
  float acc = kb[c];
  #pragma unroll
  for (int kh = 0; kh < 5; ++kh) {
    const int hh = h + kh - 2;
    if ((unsigned)hh >= HH) continue;
    #pragma unroll
    for (int kwi = 0; kwi < 5; ++kwi) {
      const int ww = w + kwi - 2;
      if ((unsigned)ww >= WW) continue;
      acc = fmaf(v[((b * HH + hh) * WW + ww) * CC + c],
                 kw[(kh * 5 + kwi) * CC + c], acc);
    }
  }
  lepe[idx] = acc;
}

// ---------------- K3: row (width-axis) attention; v1 IN PLACE over v --------
// block = (b,h,n); thread t = query position w. All global v reads staged to
// LDS before the barrier; writes only at the end; per-block regions disjoint.
__global__ __launch_bounds__(128) void rowattn_kernel(
    const bf16* __restrict__ q, const bf16* __restrict__ k,
    float* v, const float* __restrict__ mask_w) {
  __shared__ float kt[WW][36];
  __shared__ float vt[WW][36];
  const int n = blockIdx.x % NHH;
  const int h = (blockIdx.x / NHH) % HH;
  const int b = blockIdx.x / (NHH * HH);
  const int t = threadIdx.x;
  const int base = ((b * HH + h) * WW) * CC + n * KDD;
  load8bf(k + base + t * CC +  0, &kt[t][0]);
  load8bf(k + base + t * CC +  8, &kt[t][8]);
  load8bf(k + base + t * CC + 16, &kt[t][16]);
  load8bf(k + base + t * CC + 24, &kt[t][24]);
  load32f(v + base + t * CC, &vt[t][0]);
  float qr[KDD];
  load8bf(q + base + t * CC +  0, &qr[0]);
  load8bf(q + base + t * CC +  8, &qr[8]);
  load8bf(q + base + t * CC + 16, &qr[16]);
  load8bf(q + base + t * CC + 24, &qr[24]);
  __syncthreads();
  const float* mrow = mask_w + (n * WW + t) * WW;
  float m = -1e30f;
  for (int u = 0; u < WW; ++u) {
    float s = mrow[u];
    const float4* krow = reinterpret_cast<const float4*>(kt[u]);
    #pragma unroll
    for (int d4 = 0; d4 < 8; ++d4) {
      float4 kv = krow[d4];
      s = fmaf(qr[d4*4+0], kv.x, s);
      s = fmaf(qr[d4*4+1], kv.y, s);
      s = fmaf(qr[d4*4+2], kv.z, s);
      s = fmaf(qr[d4*4+3], kv.w, s);
    }
    m = fmaxf(m, s);
  }
  float l = 0.f;
  float acc[KDD];
  #pragma unroll
  for (int d = 0; d < KDD; ++d) acc[d] = 0.f;
  for (int u = 0; u < WW; ++u) {
    float s = mrow[u];
    const float4* krow = reinterpret_cast<const float4*>(kt[u]);
    #pragma unroll
    for (int d4 = 0; d4 < 8; ++d4) {
      float4 kv = krow[d4];
      s = fmaf(qr[d4*4+0], kv.x, s);
      s = fmaf(qr[d4*4+1], kv.y, s);
      s = fmaf(qr[d4*4+2], kv.z, s);
      s = fmaf(qr[d4*4+3], kv.w, s);
    }
    const float p = __expf(s - m);
    l += p;
    const float4* vrow = reinterpret_cast<const float4*>(vt[u]);
    #pragma unroll
    for (int d4 = 0; d4 < 8; ++d4) {
      float4 vv = vrow[d4];
      acc[d4*4+0] = fmaf(p, vv.x, acc[d4*4+0]);
      acc[d4*4+1] = fmaf(p, vv.y, acc[d4*4+1]);
      acc[d4*4+2] = fmaf(p, vv.z, acc[d4*4+2]);
      acc[d4*4+3] = fmaf(p, vv.w, acc[d4*4+3]);
    }
  }
  const float inv = 1.f / l;
  float4* vout = reinterpret_cast<float4*>(v + base + t * CC);
  #pragma unroll
  for (int d4 = 0; d4 < 8; ++d4) {
    vout[d4] = make_float4(acc[d4*4+0]*inv, acc[d4*4+1]*inv,
                           acc[d4*4+2]*inv, acc[d4*4+3]*inv);
  }
}

// ---------------- K4: column (height-axis) attention + lepe -----------------
// block = (b,w,n); thread t = query position h. v1 (fp32) lives in v-layout;
// pre = attn + lepe written IN PLACE over v1 (staged-before-barrier
// discipline). lepe (fp32) is read from d_out, which colattn never writes.
__global__ __launch_bounds__(128) void colattn_kernel(
    const bf16* __restrict__ q, const bf16* __restrict__ k,
    float* v1, const float* __restrict__ mask_h,
    const float* __restrict__ lepe) {
  __shared__ float kt[HH][36];
  __shared__ float vt[HH][36];
  const int n = blockIdx.x % NHH;
  const int w = (blockIdx.x / NHH) % WW;
  const int b = blockIdx.x / (NHH * WW);
  const int t = threadIdx.x;   // h (query) index; also staging row j
  const int kb_ = ((b * HH + t) * WW + w) * CC + n * KDD;  // [b,t,w,nslice]
  load8bf(k + kb_ +  0, &kt[t][0]);
  load8bf(k + kb_ +  8, &kt[t][8]);
  load8bf(k + kb_ + 16, &kt[t][16]);
  load8bf(k + kb_ + 24, &kt[t][24]);
  load32f(v1 + kb_, &vt[t][0]);   // v1[b,t,w,nslice] shares address kb_
  float qr[KDD];
  load8bf(q + kb_ +  0, &qr[0]);
  load8bf(q + kb_ +  8, &qr[8]);
  load8bf(q + kb_ + 16, &qr[16]);
  load8bf(q + kb_ + 24, &qr[24]);
  __syncthreads();
  const float* mrow = mask_h + (n * HH + t) * HH;
  float m = -1e30f;
  for (int u = 0; u < HH; ++u) {
    float s = mrow[u];
    const float4* krow = reinterpret_cast<const float4*>(kt[u]);
    #pragma unroll
    for (int d4 = 0; d4 < 8; ++d4) {
      float4 kv = krow[d4];
      s = fmaf(qr[d4*4+0], kv.x, s);
      s = fmaf(qr[d4*4+1], kv.y, s);
      s = fmaf(qr[d4*4+2], kv.z, s);
      s = fmaf(qr[d4*4+3], kv.w, s);
    }
    m = fmaxf(m, s);
  }
  float l = 0.f;
  float acc[KDD];
  #pragma unroll
  for (int d = 0; d < KDD; ++d) acc[d] = 0.f;
  for (int u = 0; u < HH; ++u) {
    float s = mrow[u];
    const float4* krow = reinterpret_cast<const float4*>(kt[u]);
    #pragma unroll
    for (int d4 = 0; d4 < 8; ++d4) {
      float4 kv = krow[d4];
      s = fmaf(qr[d4*4+0], kv.x, s);
      s = fmaf(qr[d4*4+1], kv.y, s);
      s = fmaf(qr[d4*4+2], kv.z, s);
      s = fmaf(qr[d4*4+3], kv.w, s);
    }
    const float p = __expf(s - m);
    l += p;
    const float4* vrow = reinterpret_cast<const float4*>(vt[u]);
    #pragma unroll
    for (int d4 = 0; d4 < 8; ++d4) {
      float4 vv = vrow[d4];
      acc[d4*4+0] = fmaf(p, vv.x, acc[d4*4+0]);
      acc[d4*4+1] = fmaf(p, vv.y, acc[d4*4+1]);
      acc[d4*4+2] = fmaf(p, vv.z, acc[d4*4+2]);
      acc[d4*4+3] = fmaf(p, vv.w, acc[d4*4+3]);
    }
  }
  const float inv = 1.f / l;
  float le[KDD];
  load32f(lepe + kb_, le);
  float4* pout = reinterpret_cast<float4*>(v1 + kb_);
  #pragma unroll
  for (int d4 = 0; d4 < 8; ++d4) {
    pout[d4] = make_float4(fmaf(acc[d4*4+0], inv, le[d4*4+0]),
                           fmaf(acc[d4*4+1], inv, le[d4*4+1]),
                           fmaf(acc[d4*4+2], inv, le[d4*4+2]),
                           fmaf(acc[d4*4+3], inv, le[d4*4+3]));
  }
}

// ---------------- K5: output projection (fp32 pre -> fp32 out) --------------
__global__ __launch_bounds__(192) void proj_kernel(
    const float* __restrict__ pre, const float* __restrict__ Wo,
    const float* __restrict__ bo, float* __restrict__ out) {
  __shared__ float xs[8 * CC];
  const int c = threadIdx.x;
  const int row0 = blockIdx.x * 8;
  {
    const float4* xp = reinterpret_cast<const float4*>(pre + row0 * CC) + c * 2;
    float4 a0 = xp[0], a1 = xp[1];
    xs[c*8+0] = a0.x; xs[c*8+1] = a0.y; xs[c*8+2] = a0.z; xs[c*8+3] = a0.w;
    xs[c*8+4] = a1.x; xs[c*8+5] = a1.y; xs[c*8+6] = a1.z; xs[c*8+7] = a1.w;
  }
  __syncthreads();
  float a[8];
  const float bof = bo[c];
  #pragma unroll
  for (int r = 0; r < 8; ++r) a[r] = bof;
  for (int kk = 0; kk < CC; ++kk) {
    const float wo = Wo[kk * CC + c];
    #pragma unroll
    for (int r = 0; r < 8; ++r) a[r] = fmaf(xs[r * CC + kk], wo, a[r]);
  }
  #pragma unroll
  for (int r = 0; r < 8; ++r) out[(row0 + r) * CC + c] = a[r];
}

extern "C" void kernel_launch(void* const* d_in, const int* in_sizes, int n_in,
                              void* d_out, int out_size, void* d_ws, size_t ws_size,
                              hipStream_t stream) {
  const float* x      = (const float*)d_in[0];
  const float* mask_h = (const float*)d_in[1];
  const float* mask_w = (const float*)d_in[2];
  const float* Wq = (const float*)d_in[3];
  const float* bq = (const float*)d_in[4];
  const float* Wk = (const float*)d_in[5];
  const float* bk = (const float*)d_in[6];
  const float* Wv = (const float*)d_in[7];
  const float* bv = (const float*)d_in[8];
  const float* lw = (const float*)d_in[9];
  const float* lb = (const float*)d_in[10];
  const float* Wo = (const float*)d_in[11];
  const float* bo = (const float*)d_in[12];
  float* out = (float*)d_out;   // reference output dtype is float32

  // ws: q bf16 (25.2MB) | k bf16 (25.2MB) | v fp32 (50.3MB) = 100.7 MB
  // (this exact footprint was exercised by Round 4 and produced correct
  //  values — validated under the fp32-output interpretation)
  bf16*  q    = (bf16*)d_ws;
  bf16*  kbuf = q + NTOT;
  float* v    = (float*)(kbuf + NTOT);

  qkv_kernel<<<(BB*HH*WW)/8, CC, 0, stream>>>(x, Wq, bq, Wk, bk, Wv, bv, q, kbuf, v);
  lepe_kernel<<<(NTOT + 255)/256, 256, 0, stream>>>(v, lw, lb, out);        // out = lepe (fp32)
  rowattn_kernel<<<BB*HH*NHH, WW, 0, stream>>>(q, kbuf, v, mask_w);         // v := v1
  colattn_kernel<<<BB*WW*NHH, HH, 0, stream>>>(q, kbuf, v, mask_h, out);    // v := attn+lepe
  proj_kernel<<<(BB*HH*WW)/8, CC, 0, stream>>>(v, Wo, bo, out);             // out = v@Wo+bo
}

// Round 7
// 738.188 us; speedup vs baseline: 1.6307x; 1.6307x over previous
//
#include <hip/hip_runtime.h>
#include <hip/hip_bf16.h>

#define BB  4
#define HH  128
#define WW  128
#define CC  192
#define NHH 6
#define KDD 32
#define NTOT (BB*HH*WW*CC)   // 12582912
#define SCALING 0.17677669529663687f

typedef __hip_bfloat16 bf16;
typedef short bf16x8 __attribute__((ext_vector_type(8)));
typedef float floatx4 __attribute__((ext_vector_type(4)));

__device__ __forceinline__ float b2f(bf16 v) { return __bfloat162float(v); }
__device__ __forceinline__ bf16  f2b(float v) { return __float2bfloat16(v); }
__device__ __forceinline__ unsigned short f2bs(float f) {
  union { bf16 b; unsigned short u; } c; c.b = __float2bfloat16(f); return c.u;
}

// ---------------- K1: fused QKV projection (fp32 in; q,k bf16; v fp32) ------
__global__ __launch_bounds__(192) void qkv_kernel(
    const float* __restrict__ x,
    const float* __restrict__ Wq, const float* __restrict__ bq,
    const float* __restrict__ Wk, const float* __restrict__ bk,
    const float* __restrict__ Wv, const float* __restrict__ bv,
    bf16* __restrict__ q, bf16* __restrict__ k, float* __restrict__ v) {
  __shared__ float xs[8 * CC];
  const int c = threadIdx.x;
  const int row0 = blockIdx.x * 8;
  {
    const float4* xp = reinterpret_cast<const float4*>(x + row0 * CC) + c * 2;
    float4 a0 = xp[0], a1 = xp[1];
    xs[c*8+0] = a0.x; xs[c*8+1] = a0.y; xs[c*8+2] = a0.z; xs[c*8+3] = a0.w;
    xs[c*8+4] = a1.x; xs[c*8+5] = a1.y; xs[c*8+6] = a1.z; xs[c*8+7] = a1.w;
  }
  __syncthreads();
  float aq[8], ak[8], av[8];
  const float bqf = bq[c], bkf = bk[c], bvf = bv[c];
  #pragma unroll
  for (int r = 0; r < 8; ++r) { aq[r] = bqf; ak[r] = bkf; av[r] = bvf; }
  for (int kk = 0; kk < CC; ++kk) {
    const float wq = Wq[kk * CC + c];
    const float wk = Wk[kk * CC + c];
    const float wv = Wv[kk * CC + c];
    #pragma unroll
    for (int r = 0; r < 8; ++r) {
      const float xv = xs[r * CC + kk];
      aq[r] = fmaf(xv, wq, aq[r]);
      ak[r] = fmaf(xv, wk, ak[r]);
      av[r] = fmaf(xv, wv, av[r]);
    }
  }
  #pragma unroll
  for (int r = 0; r < 8; ++r) {
    const int o = (row0 + r) * CC + c;
    q[o] = f2b(aq[r]);
    k[o] = f2b(ak[r] * SCALING);
    v[o] = av[r];
  }
}

// ---------------- K2: depthwise 5x5 conv (LEPE) -> d_out (fp32) -------------
__global__ __launch_bounds__(256) void lepe_kernel(
    const float* __restrict__ v, const float* __restrict__ kw,
    const float* __restrict__ kb, float* __restrict__ lepe) {
  const int idx = blockIdx.x * 256 + threadIdx.x;
  if (idx >= NTOT) return;
  const int c = idx % CC;
  const int w = (idx / CC) % WW;
  const int h = (idx / (CC * WW)) % HH;
  const int b = idx / (CC * WW * HH);
  float acc = kb[c];
  #pragma unroll
  for (int kh = 0; kh < 5; ++kh) {
    const int hh = h + kh - 2;
    if ((unsigned)hh >= HH) continue;
    #pragma unroll
    for (int kwi = 0; kwi < 5; ++kwi) {
      const int ww = w + kwi - 2;
      if ((unsigned)ww >= WW) continue;
      acc = fmaf(v[((b * HH + hh) * WW + ww) * CC + c],
                 kw[(kh * 5 + kwi) * CC + c], acc);
    }
  }
  lepe[idx] = acc;
}

// ---------------- K3/K4: MFMA attention (row or column axis) ----------------
// One wave (64 threads) per (b, line p, head n). S = 128x128 in 16x16 tiles,
// full (non-online) softmax, P round-trip through LDS into A-layout, PV via
// MFMA. v1 (or pre=attn+lepe) written IN PLACE over vbuf: all V reads are
// pulled into registers before any write; per-block regions are disjoint.
// MFMA layouts (gfx950, 16x16x32 bf16; learn_hip m89/m91/m120 verified):
//   A[m=lane&15][k=quad*8+j]   B[k=quad*8+j][n=lane&15]
//   C/D: col=lane&15, row=quad*4+reg
__global__ __launch_bounds__(64) void attn_mfma_kernel(
    const bf16* __restrict__ qg, const bf16* __restrict__ kg,
    float* vbuf, const float* __restrict__ mask,
    const float* __restrict__ lepeadd, const int rstride, const int is_col) {
  __shared__ unsigned short P[16 * 136];   // P band, row stride 136 (16B-aligned)
  const int bx = blockIdx.x;
  const int n = bx % NHH;
  const int p = (bx / NHH) % 128;
  const int b = bx / (NHH * 128);
  const int base = is_col ? ((b * HH * WW + p) * CC + n * KDD)
                          : (((b * HH + p) * WW) * CC + n * KDD);
  const int l = threadIdx.x;
  const int r16 = l & 15, quad = l >> 4;
  const float* mbase = mask + n * 128 * 128;
  const floatx4 zero = {0.f, 0.f, 0.f, 0.f};

  // K fragments: B[k=dim][n=key] — lane holds 8 contiguous dims of its key row
  bf16x8 kf[8];
  #pragma unroll
  for (int ni = 0; ni < 8; ++ni) {
    kf[ni] = *reinterpret_cast<const bf16x8*>(
        kg + base + (ni * 16 + r16) * rstride + quad * 8);
  }
  // V fragments for PV: B[k=key][n=dim] — 8 strided fp32 loads per frag,
  // converted to bf16. Loaded BEFORE any in-place write (correctness).
  bf16x8 vf[4][2];
  #pragma unroll
  for (int s = 0; s < 4; ++s) {
    #pragma unroll
    for (int nj = 0; nj < 2; ++nj) {
      bf16x8 t;
      #pragma unroll
      for (int j = 0; j < 8; ++j) {
        const int key = s * 32 + quad * 8 + j;
        t[j] = (short)f2bs(vbuf[base + key * rstride + nj * 16 + r16]);
      }
      vf[s][nj] = t;
    }
  }

  for (int mi = 0; mi < 8; ++mi) {
    bf16x8 qf = *reinterpret_cast<const bf16x8*>(
        qg + base + (mi * 16 + r16) * rstride + quad * 8);
    floatx4 S[8];
    #pragma unroll
    for (int ni = 0; ni < 8; ++ni)
      S[ni] = __builtin_amdgcn_mfma_f32_16x16x32_bf16(qf, kf[ni], zero, 0, 0, 0);
    // + mask  (element (reg i, lane): query=mi*16+quad*4+i, key=ni*16+r16)
    #pragma unroll
    for (int ni = 0; ni < 8; ++ni)
      #pragma unroll
      for (int i = 0; i < 4; ++i)
        S[ni][i] += mbase[(mi * 16 + quad * 4 + i) * 128 + ni * 16 + r16];
    // row max + exp + row sum (row lives across 16 lanes of the quad-group)
    float linv[4], mrow[4];
    #pragma unroll
    for (int i = 0; i < 4; ++i) {
      float m = S[0][i];
      #pragma unroll
      for (int ni = 1; ni < 8; ++ni) m = fmaxf(m, S[ni][i]);
      m = fmaxf(m, __shfl_xor(m, 1));
      m = fmaxf(m, __shfl_xor(m, 2));
      m = fmaxf(m, __shfl_xor(m, 4));
      m = fmaxf(m, __shfl_xor(m, 8));
      mrow[i] = m;
    }
    #pragma unroll
    for (int i = 0; i < 4; ++i) {
      float lsum = 0.f;
      #pragma unroll
      for (int ni = 0; ni < 8; ++ni) {
        const float pv = __expf(S[ni][i] - mrow[i]);
        S[ni][i] = pv;
        lsum += pv;
      }
      lsum += __shfl_xor(lsum, 1);
      lsum += __shfl_xor(lsum, 2);
      lsum += __shfl_xor(lsum, 4);
      lsum += __shfl_xor(lsum, 8);
      linv[i] = 1.f / lsum;
    }
    // P (normalized, bf16) -> LDS in [query][key] row-major, stride 136
    #pragma unroll
    for (int ni = 0; ni < 8; ++ni)
      #pragma unroll
      for (int i = 0; i < 4; ++i)
        P[(quad * 4 + i) * 136 + ni * 16 + r16] = f2bs(S[ni][i] * linv[i]);
    // PV: A-frag = 8 contiguous keys of P row r16
    floatx4 O[2] = {zero, zero};
    #pragma unroll
    for (int s = 0; s < 4; ++s) {
      bf16x8 pf = *reinterpret_cast<const bf16x8*>(
          &P[r16 * 136 + s * 32 + quad * 8]);
      #pragma unroll
      for (int nj = 0; nj < 2; ++nj)
        O[nj] = __builtin_amdgcn_mfma_f32_16x16x32_bf16(pf, vf[s][nj], O[nj], 0, 0, 0);
    }
    // write out (in place over vbuf); element: query=mi*16+quad*4+i, dim=nj*16+r16
    #pragma unroll
    for (int nj = 0; nj < 2; ++nj)
      #pragma unroll
      for (int i = 0; i < 4; ++i) {
        const int addr = base + (mi * 16 + quad * 4 + i) * rstride + nj * 16 + r16;
        float val = O[nj][i];
        if (lepeadd) val += lepeadd[addr];
        vbuf[addr] = val;
      }
  }
}

// ---------------- K5: output projection (fp32 pre -> fp32 out) --------------
__global__ __launch_bounds__(192) void proj_kernel(
    const float* __restrict__ pre, const float* __restrict__ Wo,
    const float* __restrict__ bo, float* __restrict__ out) {
  __shared__ float xs[8 * CC];
  const int c = threadIdx.x;
  const int row0 = blockIdx.x * 8;
  {
    const float4* xp = reinterpret_cast<const float4*>(pre + row0 * CC) + c * 2;
    float4 a0 = xp[0], a1 = xp[1];
    xs[c*8+0] = a0.x; xs[c*8+1] = a0.y; xs[c*8+2] = a0.z; xs[c*8+3] = a0.w;
    xs[c*8+4] = a1.x; xs[c*8+5] = a1.y; xs[c*8+6] = a1.z; xs[c*8+7] = a1.w;
  }
  __syncthreads();
  float a[8];
  const float bof = bo[c];
  #pragma unroll
  for (int r = 0; r < 8; ++r) a[r] = bof;
  for (int kk = 0; kk < CC; ++kk) {
    const float wo = Wo[kk * CC + c];
    #pragma unroll
    for (int r = 0; r < 8; ++r) a[r] = fmaf(xs[r * CC + kk], wo, a[r]);
  }
  #pragma unroll
  for (int r = 0; r < 8; ++r) out[(row0 + r) * CC + c] = a[r];
}

extern "C" void kernel_launch(void* const* d_in, const int* in_sizes, int n_in,
                              void* d_out, int out_size, void* d_ws, size_t ws_size,
                              hipStream_t stream) {
  const float* x      = (const float*)d_in[0];
  const float* mask_h = (const float*)d_in[1];
  const float* mask_w = (const float*)d_in[2];
  const float* Wq = (const float*)d_in[3];
  const float* bq = (const float*)d_in[4];
  const float* Wk = (const float*)d_in[5];
  const float* bk = (const float*)d_in[6];
  const float* Wv = (const float*)d_in[7];
  const float* bv = (const float*)d_in[8];
  const float* lw = (const float*)d_in[9];
  const float* lb = (const float*)d_in[10];
  const float* Wo = (const float*)d_in[11];
  const float* bo = (const float*)d_in[12];
  float* out = (float*)d_out;

  // ws: q bf16 (25.2MB) | k bf16 (25.2MB) | v fp32 (50.3MB) = 100.7 MB
  bf16*  q    = (bf16*)d_ws;
  bf16*  kbuf = q + NTOT;
  float* v    = (float*)(kbuf + NTOT);

  qkv_kernel<<<(BB*HH*WW)/8, CC, 0, stream>>>(x, Wq, bq, Wk, bk, Wv, bv, q, kbuf, v);
  lepe_kernel<<<(NTOT + 255)/256, 256, 0, stream>>>(v, lw, lb, out);   // out = lepe
  // row attention: lines are rows (h fixed), stride CC; v := v1
  attn_mfma_kernel<<<BB*128*NHH, 64, 0, stream>>>(
      q, kbuf, v, mask_w, nullptr, CC, 0);
  // column attention: lines are columns (w fixed), stride WW*CC; v := attn+lepe
  attn_mfma_kernel<<<BB*128*NHH, 64, 0, stream>>>(
      q, kbuf, v, mask_h, out, WW*CC, 1);
  proj_kernel<<<(BB*HH*WW)/8, CC, 0, stream>>>(v, Wo, bo, out);        // out = v@Wo+bo
}

// Round 8
// 575.912 us; speedup vs baseline: 2.0902x; 1.2818x over previous
//
#include <hip/hip_runtime.h>
#include <hip/hip_bf16.h>

#define BB  4
#define HH  128
#define WW  128
#define CC  192
#define NHH 6
#define KDD 32
#define NTOT (BB*HH*WW*CC)   // 12582912
#define SCALING 0.17677669529663687f

typedef __hip_bfloat16 bf16;
typedef short bf16x8 __attribute__((ext_vector_type(8)));
typedef float floatx4 __attribute__((ext_vector_type(4)));

__device__ __forceinline__ float b2f(bf16 v) { return __bfloat162float(v); }
__device__ __forceinline__ bf16  f2b(float v) { return __float2bfloat16(v); }
__device__ __forceinline__ unsigned short f2bs(float f) {
  union { bf16 b; unsigned short u; } c; c.b = __float2bfloat16(f); return c.u;
}

// ---------------- K0: weight prep — transpose fp32 W -> bf16 Wt[n][k] -------
// Wt order: Wq | Wk(*SCALING) | Wv | Wo, each 192x192.
__global__ __launch_bounds__(256) void prep_kernel(
    const float* __restrict__ Wq, const float* __restrict__ Wk,
    const float* __restrict__ Wv, const float* __restrict__ Wo,
    unsigned short* __restrict__ Wt) {
  const int idx = blockIdx.x * 256 + threadIdx.x;   // 4*36864 total
  if (idx >= 4 * CC * CC) return;
  const int mat = idx / (CC * CC);
  const int rem = idx % (CC * CC);
  const int kk = rem / CC;      // k index
  const int nn = rem % CC;      // n index (fastest -> coalesced fp32 reads)
  const float* W = (mat == 0) ? Wq : (mat == 1) ? Wk : (mat == 2) ? Wv : Wo;
  float val = W[kk * CC + nn];
  if (mat == 1) val *= SCALING;
  Wt[mat * CC * CC + nn * CC + kk] = f2bs(val);
}

// ---------------- K1: QKV projection via MFMA (q,k,v all bf16) --------------
// Block = 256 thr = 4 waves; wave handles 16 rows x 192 cols x 3 matrices.
// MFMA 16x16x32 bf16 layouts (verified in-round):
//   A[m=lane&15][k=quad*8+j], B[k=quad*8+j][n=lane&15], C/D col=lane&15 row=quad*4+reg
__global__ __launch_bounds__(256) void qkv_mfma(
    const float* __restrict__ x, const unsigned short* __restrict__ Wt,
    const float* __restrict__ bq, const float* __restrict__ bk,
    const float* __restrict__ bv,
    bf16* __restrict__ q, bf16* __restrict__ k, bf16* __restrict__ v) {
  const int wave = threadIdx.x >> 6, l = threadIdx.x & 63;
  const int r16 = l & 15, quad = l >> 4;
  const int row0 = blockIdx.x * 64 + wave * 16;
  const floatx4 zero = {0.f, 0.f, 0.f, 0.f};
  // A-frags: 16 rows x K=192 (fp32 -> bf16)
  bf16x8 a[6];
  const float* xrow = x + (row0 + r16) * CC;
  #pragma unroll
  for (int kc = 0; kc < 6; ++kc) {
    const float4* p = reinterpret_cast<const float4*>(xrow + kc * 32 + quad * 8);
    float4 u0 = p[0], u1 = p[1];
    bf16x8 t;
    t[0]=f2bs(u0.x); t[1]=f2bs(u0.y); t[2]=f2bs(u0.z); t[3]=f2bs(u0.w);
    t[4]=f2bs(u1.x); t[5]=f2bs(u1.y); t[6]=f2bs(u1.z); t[7]=f2bs(u1.w);
    a[kc] = t;
  }
  #pragma unroll
  for (int mat = 0; mat < 3; ++mat) {
    const unsigned short* Wm = Wt + mat * CC * CC;
    bf16* outp = (mat == 0) ? q : (mat == 1) ? k : v;
    const float* bias = (mat == 0) ? bq : (mat == 1) ? bk : bv;
    const float bscale = (mat == 1) ? SCALING : 1.f;
    #pragma unroll
    for (int nt = 0; nt < 12; ++nt) {
      floatx4 acc = zero;
      #pragma unroll
      for (int kc = 0; kc < 6; ++kc) {
        bf16x8 bfr = *reinterpret_cast<const bf16x8*>(
            Wm + (nt * 16 + r16) * CC + kc * 32 + quad * 8);
        acc = __builtin_amdgcn_mfma_f32_16x16x32_bf16(a[kc], bfr, acc, 0, 0, 0);
      }
      const int col = nt * 16 + r16;
      const float bf_ = bias[col] * bscale;
      #pragma unroll
      for (int i = 0; i < 4; ++i)
        outp[(row0 + quad * 4 + i) * CC + col] = f2b(acc[i] + bf_);
    }
  }
}

// ---------------- K2: depthwise 5x5 conv (LEPE, bf16 v) -> d_out (fp32) -----
__global__ __launch_bounds__(256) void lepe_kernel(
    const bf16* __restrict__ v, const float* __restrict__ kw,
    const float* __restrict__ kb, float* __restrict__ lepe) {
  const int idx = blockIdx.x * 256 + threadIdx.x;
  if (idx >= NTOT) return;
  const int c = idx % CC;
  const int w = (idx / CC) % WW;
  const int h = (idx / (CC * WW)) % HH;
  const int b = idx / (CC * WW * HH);
  float acc = kb[c];
  #pragma unroll
  for (int kh = 0; kh < 5; ++kh) {
    const int hh = h + kh - 2;
    if ((unsigned)hh >= HH) continue;
    #pragma unroll
    for (int kwi = 0; kwi < 5; ++kwi) {
      const int ww = w + kwi - 2;
      if ((unsigned)ww >= WW) continue;
      acc = fmaf(b2f(v[((b * HH + hh) * WW + ww) * CC + c]),
                 kw[(kh * 5 + kwi) * CC + c], acc);
    }
  }
  lepe[idx] = acc;
}

// ---------------- K3/K4: MFMA attention (row or column axis) ----------------
// One wave per (b, line p, head n). vbuf is bf16; v1 / pre=attn+lepe written
// IN PLACE (all V reads pulled to registers before any write; per-block
// regions disjoint).
__global__ __launch_bounds__(64) void attn_mfma_kernel(
    const bf16* __restrict__ qg, const bf16* __restrict__ kg,
    bf16* vbuf, const float* __restrict__ mask,
    const float* __restrict__ lepeadd, const int rstride, const int is_col) {
  __shared__ unsigned short P[16 * 136];
  const int bx = blockIdx.x;
  const int n = bx % NHH;
  const int p = (bx / NHH) % 128;
  const int b = bx / (NHH * 128);
  const int base = is_col ? ((b * HH * WW + p) * CC + n * KDD)
                          : (((b * HH + p) * WW) * CC + n * KDD);
  const int l = threadIdx.x;
  const int r16 = l & 15, quad = l >> 4;
  const float* mbase = mask + n * 128 * 128;
  const floatx4 zero = {0.f, 0.f, 0.f, 0.f};
  const short* vs = (const short*)vbuf;

  bf16x8 kf[8];
  #pragma unroll
  for (int ni = 0; ni < 8; ++ni) {
    kf[ni] = *reinterpret_cast<const bf16x8*>(
        kg + base + (ni * 16 + r16) * rstride + quad * 8);
  }
  // V fragments: B[k=key][n=dim] — strided bf16 scalar loads (before writes)
  bf16x8 vf[4][2];
  #pragma unroll
  for (int s = 0; s < 4; ++s) {
    #pragma unroll
    for (int nj = 0; nj < 2; ++nj) {
      bf16x8 t;
      #pragma unroll
      for (int j = 0; j < 8; ++j) {
        const int key = s * 32 + quad * 8 + j;
        t[j] = vs[base + key * rstride + nj * 16 + r16];
      }
      vf[s][nj] = t;
    }
  }

  for (int mi = 0; mi < 8; ++mi) {
    bf16x8 qf = *reinterpret_cast<const bf16x8*>(
        qg + base + (mi * 16 + r16) * rstride + quad * 8);
    floatx4 S[8];
    #pragma unroll
    for (int ni = 0; ni < 8; ++ni)
      S[ni] = __builtin_amdgcn_mfma_f32_16x16x32_bf16(qf, kf[ni], zero, 0, 0, 0);
    #pragma unroll
    for (int ni = 0; ni < 8; ++ni)
      #pragma unroll
      for (int i = 0; i < 4; ++i)
        S[ni][i] += mbase[(mi * 16 + quad * 4 + i) * 128 + ni * 16 + r16];
    float linv[4], mrow[4];
    #pragma unroll
    for (int i = 0; i < 4; ++i) {
      float m = S[0][i];
      #pragma unroll
      for (int ni = 1; ni < 8; ++ni) m = fmaxf(m, S[ni][i]);
      m = fmaxf(m, __shfl_xor(m, 1));
      m = fmaxf(m, __shfl_xor(m, 2));
      m = fmaxf(m, __shfl_xor(m, 4));
      m = fmaxf(m, __shfl_xor(m, 8));
      mrow[i] = m;
    }
    #pragma unroll
    for (int i = 0; i < 4; ++i) {
      float lsum = 0.f;
      #pragma unroll
      for (int ni = 0; ni < 8; ++ni) {
        const float pv = __expf(S[ni][i] - mrow[i]);
        S[ni][i] = pv;
        lsum += pv;
      }
      lsum += __shfl_xor(lsum, 1);
      lsum += __shfl_xor(lsum, 2);
      lsum += __shfl_xor(lsum, 4);
      lsum += __shfl_xor(lsum, 8);
      linv[i] = 1.f / lsum;
    }
    #pragma unroll
    for (int ni = 0; ni < 8; ++ni)
      #pragma unroll
      for (int i = 0; i < 4; ++i)
        P[(quad * 4 + i) * 136 + ni * 16 + r16] = f2bs(S[ni][i] * linv[i]);
    floatx4 O[2] = {zero, zero};
    #pragma unroll
    for (int s = 0; s < 4; ++s) {
      bf16x8 pf = *reinterpret_cast<const bf16x8*>(
          &P[r16 * 136 + s * 32 + quad * 8]);
      #pragma unroll
      for (int nj = 0; nj < 2; ++nj)
        O[nj] = __builtin_amdgcn_mfma_f32_16x16x32_bf16(pf, vf[s][nj], O[nj], 0, 0, 0);
    }
    #pragma unroll
    for (int nj = 0; nj < 2; ++nj)
      #pragma unroll
      for (int i = 0; i < 4; ++i) {
        const int addr = base + (mi * 16 + quad * 4 + i) * rstride + nj * 16 + r16;
        float val = O[nj][i];
        if (lepeadd) val += lepeadd[addr];
        vbuf[addr] = f2b(val);
      }
  }
}

// ---------------- K5: output projection via MFMA (bf16 pre -> fp32 out) -----
__global__ __launch_bounds__(256) void proj_mfma(
    const bf16* __restrict__ pre, const unsigned short* __restrict__ Wto,
    const float* __restrict__ bo, float* __restrict__ out) {
  const int wave = threadIdx.x >> 6, l = threadIdx.x & 63;
  const int r16 = l & 15, quad = l >> 4;
  const int row0 = blockIdx.x * 64 + wave * 16;
  const floatx4 zero = {0.f, 0.f, 0.f, 0.f};
  bf16x8 a[6];
  #pragma unroll
  for (int kc = 0; kc < 6; ++kc)
    a[kc] = *reinterpret_cast<const bf16x8*>(
        pre + (row0 + r16) * CC + kc * 32 + quad * 8);
  #pragma unroll
  for (int nt = 0; nt < 12; ++nt) {
    floatx4 acc = zero;
    #pragma unroll
    for (int kc = 0; kc < 6; ++kc) {
      bf16x8 bfr = *reinterpret_cast<const bf16x8*>(
          Wto + (nt * 16 + r16) * CC + kc * 32 + quad * 8);
      acc = __builtin_amdgcn_mfma_f32_16x16x32_bf16(a[kc], bfr, acc, 0, 0, 0);
    }
    const int col = nt * 16 + r16;
    const float bf_ = bo[col];
    #pragma unroll
    for (int i = 0; i < 4; ++i)
      out[(row0 + quad * 4 + i) * CC + col] = acc[i] + bf_;
  }
}

extern "C" void kernel_launch(void* const* d_in, const int* in_sizes, int n_in,
                              void* d_out, int out_size, void* d_ws, size_t ws_size,
                              hipStream_t stream) {
  const float* x      = (const float*)d_in[0];
  const float* mask_h = (const float*)d_in[1];
  const float* mask_w = (const float*)d_in[2];
  const float* Wq = (const float*)d_in[3];
  const float* bq = (const float*)d_in[4];
  const float* Wk = (const float*)d_in[5];
  const float* bk = (const float*)d_in[6];
  const float* Wv = (const float*)d_in[7];
  const float* bv = (const float*)d_in[8];
  const float* lw = (const float*)d_in[9];
  const float* lb = (const float*)d_in[10];
  const float* Wo = (const float*)d_in[11];
  const float* bo = (const float*)d_in[12];
  float* out = (float*)d_out;

  // ws: q bf16 | k bf16 | v bf16 (each NTOT) | Wt bf16 4x192x192 = 75.8 MB
  bf16* q    = (bf16*)d_ws;
  bf16* kbuf = q + NTOT;
  bf16* v    = kbuf + NTOT;
  unsigned short* Wt = (unsigned short*)(v + NTOT);

  prep_kernel<<<(4*CC*CC + 255)/256, 256, 0, stream>>>(Wq, Wk, Wv, Wo, Wt);
  qkv_mfma<<<(BB*HH*WW)/64, 256, 0, stream>>>(x, Wt, bq, bk, bv, q, kbuf, v);
  lepe_kernel<<<(NTOT + 255)/256, 256, 0, stream>>>(v, lw, lb, out);   // out = lepe
  attn_mfma_kernel<<<BB*128*NHH, 64, 0, stream>>>(
      q, kbuf, v, mask_w, nullptr, CC, 0);                  // v := v1
  attn_mfma_kernel<<<BB*128*NHH, 64, 0, stream>>>(
      q, kbuf, v, mask_h, out, WW*CC, 1);                   // v := attn+lepe
  proj_mfma<<<(BB*HH*WW)/64, 256, 0, stream>>>(v, Wt + 3*CC*CC, bo, out);
}

// Round 9
// 414.037 us; speedup vs baseline: 2.9074x; 1.3910x over previous
//
#include <hip/hip_runtime.h>
#include <hip/hip_bf16.h>

#define BB  4
#define HH  128
#define WW  128
#define CC  192
#define NHH 6
#define KDD 32
#define NTOT (BB*HH*WW*CC)   // 12582912
#define SCALING 0.17677669529663687f

typedef __hip_bfloat16 bf16;
typedef short bf16x8 __attribute__((ext_vector_type(8)));
typedef float floatx4 __attribute__((ext_vector_type(4)));

__device__ __forceinline__ float b2f(bf16 v) { return __bfloat162float(v); }
__device__ __forceinline__ bf16  f2b(float v) { return __float2bfloat16(v); }
__device__ __forceinline__ unsigned short f2bs(float f) {
  union { bf16 b; unsigned short u; } c; c.b = __float2bfloat16(f); return c.u;
}
__device__ __forceinline__ float s2f(short s) {
  union { unsigned u; float f; } c;
  c.u = ((unsigned)(unsigned short)s) << 16; return c.f;
}

// ---------------- K0: weight prep — transpose fp32 W -> bf16 Wt[n][k] -------
// Wt order: Wq | Wk(*SCALING) | Wv | Wo, each 192x192.
__global__ __launch_bounds__(256) void prep_kernel(
    const float* __restrict__ Wq, const float* __restrict__ Wk,
    const float* __restrict__ Wv, const float* __restrict__ Wo,
    unsigned short* __restrict__ Wt) {
  const int idx = blockIdx.x * 256 + threadIdx.x;   // 4*36864 total
  if (idx >= 4 * CC * CC) return;
  const int mat = idx / (CC * CC);
  const int rem = idx % (CC * CC);
  const int kk = rem / CC;
  const int nn = rem % CC;
  const float* W = (mat == 0) ? Wq : (mat == 1) ? Wk : (mat == 2) ? Wv : Wo;
  float val = W[kk * CC + nn];
  if (mat == 1) val *= SCALING;
  Wt[mat * CC * CC + nn * CC + kk] = f2bs(val);
}

// ---------------- K1: QKV projection via MFMA (q,k,v all bf16) --------------
__global__ __launch_bounds__(256) void qkv_mfma(
    const float* __restrict__ x, const unsigned short* __restrict__ Wt,
    const float* __restrict__ bq, const float* __restrict__ bk,
    const float* __restrict__ bv,
    bf16* __restrict__ q, bf16* __restrict__ k, bf16* __restrict__ v) {
  const int wave = threadIdx.x >> 6, l = threadIdx.x & 63;
  const int r16 = l & 15, quad = l >> 4;
  const int row0 = blockIdx.x * 64 + wave * 16;
  const floatx4 zero = {0.f, 0.f, 0.f, 0.f};
  bf16x8 a[6];
  const float* xrow = x + (row0 + r16) * CC;
  #pragma unroll
  for (int kc = 0; kc < 6; ++kc) {
    const float4* p = reinterpret_cast<const float4*>(xrow + kc * 32 + quad * 8);
    float4 u0 = p[0], u1 = p[1];
    bf16x8 t;
    t[0]=f2bs(u0.x); t[1]=f2bs(u0.y); t[2]=f2bs(u0.z); t[3]=f2bs(u0.w);
    t[4]=f2bs(u1.x); t[5]=f2bs(u1.y); t[6]=f2bs(u1.z); t[7]=f2bs(u1.w);
    a[kc] = t;
  }
  #pragma unroll
  for (int mat = 0; mat < 3; ++mat) {
    const unsigned short* Wm = Wt + mat * CC * CC;
    bf16* outp = (mat == 0) ? q : (mat == 1) ? k : v;
    const float* bias = (mat == 0) ? bq : (mat == 1) ? bk : bv;
    const float bscale = (mat == 1) ? SCALING : 1.f;
    #pragma unroll
    for (int nt = 0; nt < 12; ++nt) {
      floatx4 acc = zero;
      #pragma unroll
      for (int kc = 0; kc < 6; ++kc) {
        bf16x8 bfr = *reinterpret_cast<const bf16x8*>(
            Wm + (nt * 16 + r16) * CC + kc * 32 + quad * 8);
        acc = __builtin_amdgcn_mfma_f32_16x16x32_bf16(a[kc], bfr, acc, 0, 0, 0);
      }
      const int col = nt * 16 + r16;
      const float bf_ = bias[col] * bscale;
      #pragma unroll
      for (int i = 0; i < 4; ++i)
        outp[(row0 + quad * 4 + i) * CC + col] = f2b(acc[i] + bf_);
    }
  }
}

// ---------------- K2: depthwise 5x5 conv (LEPE), 8 channels/thread ----------
// One thread per (b,h,w, c8-group). bf16x8 v loads, float4 kw loads (19.2 KB
// table L1-resident), float4 stores. Same tap order + fp32 accumulation as
// the scalar version -> bit-identical output.
__global__ __launch_bounds__(256) void lepe_kernel(
    const bf16* __restrict__ v, const float* __restrict__ kw,
    const float* __restrict__ kb, float* __restrict__ lepe) {
  const int tid = blockIdx.x * 256 + threadIdx.x;    // NTOT/8 threads
  const int c8 = tid % (CC / 8);
  const int w  = (tid / (CC / 8)) % WW;
  const int h  = (tid / ((CC / 8) * WW)) % HH;
  const int b  = tid / ((CC / 8) * WW * HH);
  const int c0 = c8 * 8;
  float acc[8];
  {
    const float4* kbp = reinterpret_cast<const float4*>(kb + c0);
    float4 b0 = kbp[0], b1 = kbp[1];
    acc[0]=b0.x; acc[1]=b0.y; acc[2]=b0.z; acc[3]=b0.w;
    acc[4]=b1.x; acc[5]=b1.y; acc[6]=b1.z; acc[7]=b1.w;
  }
  #pragma unroll
  for (int kh = 0; kh < 5; ++kh) {
    const int hh = h + kh - 2;
    if ((unsigned)hh >= HH) continue;
    #pragma unroll
    for (int kwi = 0; kwi < 5; ++kwi) {
      const int ww = w + kwi - 2;
      if ((unsigned)ww >= WW) continue;
      bf16x8 vv = *reinterpret_cast<const bf16x8*>(
          v + ((b * HH + hh) * WW + ww) * CC + c0);
      const float4* kp = reinterpret_cast<const float4*>(
          kw + (kh * 5 + kwi) * CC + c0);
      float4 k0 = kp[0], k1 = kp[1];
      acc[0] = fmaf(s2f(vv[0]), k0.x, acc[0]);
      acc[1] = fmaf(s2f(vv[1]), k0.y, acc[1]);
      acc[2] = fmaf(s2f(vv[2]), k0.z, acc[2]);
      acc[3] = fmaf(s2f(vv[3]), k0.w, acc[3]);
      acc[4] = fmaf(s2f(vv[4]), k1.x, acc[4]);
      acc[5] = fmaf(s2f(vv[5]), k1.y, acc[5]);
      acc[6] = fmaf(s2f(vv[6]), k1.z, acc[6]);
      acc[7] = fmaf(s2f(vv[7]), k1.w, acc[7]);
    }
  }
  float4* op = reinterpret_cast<float4*>(lepe + ((b * HH + h) * WW + w) * CC + c0);
  op[0] = make_float4(acc[0], acc[1], acc[2], acc[3]);
  op[1] = make_float4(acc[4], acc[5], acc[6], acc[7]);
}

// ---------------- K3/K4: MFMA attention (row or column axis) ----------------
__global__ __launch_bounds__(64) void attn_mfma_kernel(
    const bf16* __restrict__ qg, const bf16* __restrict__ kg,
    bf16* vbuf, const float* __restrict__ mask,
    const float* __restrict__ lepeadd, const int rstride, const int is_col) {
  __shared__ unsigned short P[16 * 136];
  const int bx = blockIdx.x;
  const int n = bx % NHH;
  const int p = (bx / NHH) % 128;
  const int b = bx / (NHH * 128);
  const int base = is_col ? ((b * HH * WW + p) * CC + n * KDD)
                          : (((b * HH + p) * WW) * CC + n * KDD);
  const int l = threadIdx.x;
  const int r16 = l & 15, quad = l >> 4;
  const float* mbase = mask + n * 128 * 128;
  const floatx4 zero = {0.f, 0.f, 0.f, 0.f};
  const short* vs = (const short*)vbuf;

  bf16x8 kf[8];
  #pragma unroll
  for (int ni = 0; ni < 8; ++ni) {
    kf[ni] = *reinterpret_cast<const bf16x8*>(
        kg + base + (ni * 16 + r16) * rstride + quad * 8);
  }
  bf16x8 vf[4][2];
  #pragma unroll
  for (int s = 0; s < 4; ++s) {
    #pragma unroll
    for (int nj = 0; nj < 2; ++nj) {
      bf16x8 t;
      #pragma unroll
      for (int j = 0; j < 8; ++j) {
        const int key = s * 32 + quad * 8 + j;
        t[j] = vs[base + key * rstride + nj * 16 + r16];
      }
      vf[s][nj] = t;
    }
  }

  for (int mi = 0; mi < 8; ++mi) {
    bf16x8 qf = *reinterpret_cast<const bf16x8*>(
        qg + base + (mi * 16 + r16) * rstride + quad * 8);
    floatx4 S[8];
    #pragma unroll
    for (int ni = 0; ni < 8; ++ni)
      S[ni] = __builtin_amdgcn_mfma_f32_16x16x32_bf16(qf, kf[ni], zero, 0, 0, 0);
    #pragma unroll
    for (int ni = 0; ni < 8; ++ni)
      #pragma unroll
      for (int i = 0; i < 4; ++i)
        S[ni][i] += mbase[(mi * 16 + quad * 4 + i) * 128 + ni * 16 + r16];
    float linv[4], mrow[4];
    #pragma unroll
    for (int i = 0; i < 4; ++i) {
      float m = S[0][i];
      #pragma unroll
      for (int ni = 1; ni < 8; ++ni) m = fmaxf(m, S[ni][i]);
      m = fmaxf(m, __shfl_xor(m, 1));
      m = fmaxf(m, __shfl_xor(m, 2));
      m = fmaxf(m, __shfl_xor(m, 4));
      m = fmaxf(m, __shfl_xor(m, 8));
      mrow[i] = m;
    }
    #pragma unroll
    for (int i = 0; i < 4; ++i) {
      float lsum = 0.f;
      #pragma unroll
      for (int ni = 0; ni < 8; ++ni) {
        const float pv = __expf(S[ni][i] - mrow[i]);
        S[ni][i] = pv;
        lsum += pv;
      }
      lsum += __shfl_xor(lsum, 1);
      lsum += __shfl_xor(lsum, 2);
      lsum += __shfl_xor(lsum, 4);
      lsum += __shfl_xor(lsum, 8);
      linv[i] = 1.f / lsum;
    }
    #pragma unroll
    for (int ni = 0; ni < 8; ++ni)
      #pragma unroll
      for (int i = 0; i < 4; ++i)
        P[(quad * 4 + i) * 136 + ni * 16 + r16] = f2bs(S[ni][i] * linv[i]);
    floatx4 O[2] = {zero, zero};
    #pragma unroll
    for (int s = 0; s < 4; ++s) {
      bf16x8 pf = *reinterpret_cast<const bf16x8*>(
          &P[r16 * 136 + s * 32 + quad * 8]);
      #pragma unroll
      for (int nj = 0; nj < 2; ++nj)
        O[nj] = __builtin_amdgcn_mfma_f32_16x16x32_bf16(pf, vf[s][nj], O[nj], 0, 0, 0);
    }
    #pragma unroll
    for (int nj = 0; nj < 2; ++nj)
      #pragma unroll
      for (int i = 0; i < 4; ++i) {
        const int addr = base + (mi * 16 + quad * 4 + i) * rstride + nj * 16 + r16;
        float val = O[nj][i];
        if (lepeadd) val += lepeadd[addr];
        vbuf[addr] = f2b(val);
      }
  }
}

// ---------------- K5: output projection via MFMA (bf16 pre -> fp32 out) -----
__global__ __launch_bounds__(256) void proj_mfma(
    const bf16* __restrict__ pre, const unsigned short* __restrict__ Wto,
    const float* __restrict__ bo, float* __restrict__ out) {
  const int wave = threadIdx.x >> 6, l = threadIdx.x & 63;
  const int r16 = l & 15, quad = l >> 4;
  const int row0 = blockIdx.x * 64 + wave * 16;
  const floatx4 zero = {0.f, 0.f, 0.f, 0.f};
  bf16x8 a[6];
  #pragma unroll
  for (int kc = 0; kc < 6; ++kc)
    a[kc] = *reinterpret_cast<const bf16x8*>(
        pre + (row0 + r16) * CC + kc * 32 + quad * 8);
  #pragma unroll
  for (int nt = 0; nt < 12; ++nt) {
    floatx4 acc = zero;
    #pragma unroll
    for (int kc = 0; kc < 6; ++kc) {
      bf16x8 bfr = *reinterpret_cast<const bf16x8*>(
          Wto + (nt * 16 + r16) * CC + kc * 32 + quad * 8);
      acc = __builtin_amdgcn_mfma_f32_16x16x32_bf16(a[kc], bfr, acc, 0, 0, 0);
    }
    const int col = nt * 16 + r16;
    const float bf_ = bo[col];
    #pragma unroll
    for (int i = 0; i < 4; ++i)
      out[(row0 + quad * 4 + i) * CC + col] = acc[i] + bf_;
  }
}

extern "C" void kernel_launch(void* const* d_in, const int* in_sizes, int n_in,
                              void* d_out, int out_size, void* d_ws, size_t ws_size,
                              hipStream_t stream) {
  const float* x      = (const float*)d_in[0];
  const float* mask_h = (const float*)d_in[1];
  const float* mask_w = (const float*)d_in[2];
  const float* Wq = (const float*)d_in[3];
  const float* bq = (const float*)d_in[4];
  const float* Wk = (const float*)d_in[5];
  const float* bk = (const float*)d_in[6];
  const float* Wv = (const float*)d_in[7];
  const float* bv = (const float*)d_in[8];
  const float* lw = (const float*)d_in[9];
  const float* lb = (const float*)d_in[10];
  const float* Wo = (const float*)d_in[11];
  const float* bo = (const float*)d_in[12];
  float* out = (float*)d_out;

  // ws: q bf16 | k bf16 | v bf16 (each NTOT) | Wt bf16 4x192x192 = 75.8 MB
  bf16* q    = (bf16*)d_ws;
  bf16* kbuf = q + NTOT;
  bf16* v    = kbuf + NTOT;
  unsigned short* Wt = (unsigned short*)(v + NTOT);

  prep_kernel<<<(4*CC*CC + 255)/256, 256, 0, stream>>>(Wq, Wk, Wv, Wo, Wt);
  qkv_mfma<<<(BB*HH*WW)/64, 256, 0, stream>>>(x, Wt, bq, bk, bv, q, kbuf, v);
  lepe_kernel<<<(NTOT/8 + 255)/256, 256, 0, stream>>>(v, lw, lb, out);  // out = lepe
  attn_mfma_kernel<<<BB*128*NHH, 64, 0, stream>>>(
      q, kbuf, v, mask_w, nullptr, CC, 0);                  // v := v1
  attn_mfma_kernel<<<BB*128*NHH, 64, 0, stream>>>(
      q, kbuf, v, mask_h, out, WW*CC, 1);                   // v := attn+lepe
  proj_mfma<<<(BB*HH*WW)/64, 256, 0, stream>>>(v, Wt + 3*CC*CC, bo, out);
}